// Round 4
// baseline (2998.112 us; speedup 1.0000x reference)
//
#include <hip/hip_runtime.h>

// LSTM forward: B=65536, T=20, I=36, H=30. Gate order i,f,g,o.
// Inputs (fp32): x[B,T,I], W_ih[4H,I], W_hh[4H,H], b_ih[4H], b_hh[4H]
// Output (fp32, concat): out[B,T,H], h_n[1,B,H], c_n[1,B,H]
//
// Ledger:
//  R4 (gate-per-wave, G-LDS exchange, 2 barriers): 525us, VALU 69%, VGPR 56.
//  R5 FAILED: launch_bounds(512,8) -> VGPR cap 64 < ~100 live -> spill, 2364us.
//  R6 FAILED: ping-pong x reg buffers (+72 VGPR) -> spill (FETCH/WRITE +100MB),
//    715us. Also: __syncthreads drains vmcnt(0), so cross-timestep prefetch
//    deferral is impossible; prefetch only hides latency WITHIN a timestep.
//  R7 (this): row-split. Wave w owns ~8 hidden units, computes all 4 gates
//    for them: c = 8 regs, h exchanged via double-buffered h_lds[2][30][64]
//    (15KB, lane-minor, conflict-free), ONE barrier/timestep, no redundant
//    phase2/tanh, 32 indep FMA chains, x refilled in-place after x-dot
//    (latency hides under h-dot before the barrier). Rows {0-7,8-15,15-22,
//    22-29}: rows 15,22 duplicated (bitwise identical) to keep all register
//    indices compile-time.

constexpr int BB = 65536;
constexpr int TT = 20;
constexpr int II = 36;
constexpr int HH = 30;
constexpr int RPW = 8;   // rows per wave (padded)

__device__ __forceinline__ float fast_sigmoid(float v) {
    float e = __expf(-v);                      // v_exp_f32
    return __builtin_amdgcn_rcpf(1.f + e);     // v_rcp_f32
}
__device__ __forceinline__ float fast_tanh(float v) {
    // 1 - 2/(exp(2v)+1): saturates to +/-1, no inf/inf NaN
    float e = __expf(2.f * v);
    return 1.f - 2.f * __builtin_amdgcn_rcpf(e + 1.f);
}

__global__ __launch_bounds__(256, 4) void lstm_fwd(
    const float* __restrict__ x,
    const float* __restrict__ Wih,   // [4H][II] row-major, gate rows i,f,g,o
    const float* __restrict__ Whh,   // [4H][HH]
    const float* __restrict__ bih,   // [4H]
    const float* __restrict__ bhh,   // [4H]
    float* __restrict__ out) {

    __shared__ float h_lds[2][HH][64];   // [buf][hidden unit][elem], 15 KB

    const int lane = threadIdx.x & 63;
    const int w = __builtin_amdgcn_readfirstlane((int)(threadIdx.x >> 6)); // 0..3
    const int n0 = (w == 0) ? 0 : (w == 1) ? 8 : (w == 2) ? 15 : 22;
    const int b = blockIdx.x * 64 + lane;

    const float* xrow = x + (size_t)b * TT * II;
    float* orow = out + (size_t)b * TT * HH;

    // wave-uniform weight/bias bases for this wave's row block -> s_load path
    const float* wiB = Wih + (size_t)n0 * II;   // row (g,r) at [(g*HH+r)*II]
    const float* whB = Whh + (size_t)n0 * HH;   // row (g,r) at [(g*HH+r)*HH]
    const float* biB = bih + n0;
    const float* bhB = bhh + n0;

    float c[RPW];
#pragma unroll
    for (int r = 0; r < RPW; r++) c[r] = 0.f;

    // zero h buffer 0 (the 4 waves' row sets cover all 30 rows)
#pragma unroll
    for (int r = 0; r < RPW; r++) h_lds[0][n0 + r][lane] = 0.f;

    // x for t=0 (144B, 16B-aligned)
    float4 xr[II / 4];
    {
        const float4* xv = (const float4*)xrow;
#pragma unroll
        for (int q = 0; q < II / 4; q++) xr[q] = xv[q];
    }
    __syncthreads();

    int p = 0;
#pragma unroll 1
    for (int t = 0; t < TT; t++) {
        // ---- x-dot: 32 independent chains, init = bias sum (scalar loads)
        float ax[RPW][4];
#pragma unroll
        for (int r = 0; r < RPW; r++)
#pragma unroll
            for (int g = 0; g < 4; g++)
                ax[r][g] = biB[g * HH + r] + bhB[g * HH + r];

#pragma unroll
        for (int q = 0; q < II / 4; q++) {
            float4 u = xr[q];
#pragma unroll
            for (int r = 0; r < RPW; r++)
#pragma unroll
                for (int g = 0; g < 4; g++) {
                    const float* wi = wiB + (g * HH + r) * II + 4 * q; // uniform
                    ax[r][g] += wi[0] * u.x;
                    ax[r][g] += wi[1] * u.y;
                    ax[r][g] += wi[2] * u.z;
                    ax[r][g] += wi[3] * u.w;
                }
        }

        // ---- refill x in place for t+1 (last x use was above). The ~900cy
        // load latency hides under the h-dot below, before the barrier.
        if (t + 1 < TT) {
            const float4* xv = (const float4*)(xrow + (t + 1) * II);
#pragma unroll
            for (int q = 0; q < II / 4; q++) xr[q] = xv[q];
        }

        // ---- h-dot in two k-chunks of 15 (caps live hv regs at 15)
#pragma unroll
        for (int half = 0; half < 2; half++) {
            float hv[15];
#pragma unroll
            for (int k = 0; k < 15; k++)
                hv[k] = h_lds[p][half * 15 + k][lane];   // b32, conflict-free
#pragma unroll
            for (int k = 0; k < 15; k++) {
#pragma unroll
                for (int r = 0; r < RPW; r++)
#pragma unroll
                    for (int g = 0; g < 4; g++)
                        ax[r][g] += whB[(g * HH + r) * HH + half * 15 + k] * hv[k];
            }
        }

        // ---- gates, state update, stores (owning wave only: no redundancy)
#pragma unroll
        for (int r = 0; r < RPW; r++) {
            float it = fast_sigmoid(ax[r][0]);
            float ft = fast_sigmoid(ax[r][1]);
            float gt = fast_tanh(ax[r][2]);
            float ot = fast_sigmoid(ax[r][3]);
            float cn = ft * c[r] + it * gt;
            c[r] = cn;
            float hn = ot * fast_tanh(cn);
            h_lds[p ^ 1][n0 + r][lane] = hn;   // dup rows: identical values
            orow[t * HH + n0 + r] = hn;        // scattered b32; L2 merges rows
        }
        __syncthreads();   // h_lds[p^1] complete; also drains x refill (hidden)
        p ^= 1;
    }

    // finals: h from the last-written buffer, c from registers
    float* hN = out + (size_t)BB * TT * HH + (size_t)b * HH;
    float* cN = out + (size_t)BB * TT * HH + (size_t)BB * HH + (size_t)b * HH;
#pragma unroll
    for (int r = 0; r < RPW; r++) {
        hN[n0 + r] = h_lds[p][n0 + r][lane];
        cN[n0 + r] = c[r];
    }
}

extern "C" void kernel_launch(void* const* d_in, const int* in_sizes, int n_in,
                              void* d_out, int out_size, void* d_ws, size_t ws_size,
                              hipStream_t stream) {
    const float* x    = (const float*)d_in[0];
    const float* w_ih = (const float*)d_in[1];
    const float* w_hh = (const float*)d_in[2];
    const float* b_ih = (const float*)d_in[3];
    const float* b_hh = (const float*)d_in[4];
    float* out = (float*)d_out;

    hipLaunchKernelGGL(lstm_fwd, dim3(BB / 64), dim3(256), 0, stream,
                       x, w_ih, w_hh, b_ih, b_hh, out);
}

// Round 5
// 2957.957 us; speedup vs baseline: 1.0136x; 1.0136x over previous
//
#include <hip/hip_runtime.h>

// LSTM forward: B=65536, T=20, I=36, H=30. Gate order i,f,g,o.
// Inputs (fp32): x[B,T,I], W_ih[4H,I], W_hh[4H,H], b_ih[4H], b_hh[4H]
// Output (fp32, concat): out[B,T,H], h_n[1,B,H], c_n[1,B,H]
//
// Ledger:
//  R4 (gate-per-wave, G-LDS exchange, 2 barriers): 525us, VALU 69%, VGPR 56.
//  R5 FAILED: launch_bounds(512,8) -> VGPR cap 64 -> spill, 2364us.
//  R6 FAILED: ping-pong x regs, (256,4): allocator chose 64 VGPR + spill, 715us.
//  R7 FAILED: row-split structure, (256,4): allocator AGAIN chose exactly 64
//    VGPR + spill (FETCH 630MB), 2850us. Diagnosis: launch_bounds' 2nd arg is
//    a MIN; LLVM maximizes occupancy in [min,10] and squeezes to the 64-VGPR
//    step, spilling to get 8 waves/EU. Grid is 4 blocks/CU anyway, so cap
//    occupancy from above too.
//  R8 (this): R7 structure + amdgpu_waves_per_eu(4,4): budget pinned at 128
//    VGPR, allocator has no incentive to spill. Live ~105 regs.

constexpr int BB = 65536;
constexpr int TT = 20;
constexpr int II = 36;
constexpr int HH = 30;
constexpr int RPW = 8;   // rows per wave (padded)

__device__ __forceinline__ float fast_sigmoid(float v) {
    float e = __expf(-v);                      // v_exp_f32
    return __builtin_amdgcn_rcpf(1.f + e);     // v_rcp_f32
}
__device__ __forceinline__ float fast_tanh(float v) {
    // 1 - 2/(exp(2v)+1): saturates to +/-1, no inf/inf NaN
    float e = __expf(2.f * v);
    return 1.f - 2.f * __builtin_amdgcn_rcpf(e + 1.f);
}

__global__ __launch_bounds__(256)
__attribute__((amdgpu_waves_per_eu(4, 4)))
void lstm_fwd(
    const float* __restrict__ x,
    const float* __restrict__ Wih,   // [4H][II] row-major, gate rows i,f,g,o
    const float* __restrict__ Whh,   // [4H][HH]
    const float* __restrict__ bih,   // [4H]
    const float* __restrict__ bhh,   // [4H]
    float* __restrict__ out) {

    __shared__ float h_lds[2][HH][64];   // [buf][hidden unit][elem], 15 KB

    const int lane = threadIdx.x & 63;
    const int w = __builtin_amdgcn_readfirstlane((int)(threadIdx.x >> 6)); // 0..3
    const int n0 = (w == 0) ? 0 : (w == 1) ? 8 : (w == 2) ? 15 : 22;
    const int b = blockIdx.x * 64 + lane;

    const float* xrow = x + (size_t)b * TT * II;
    float* orow = out + (size_t)b * TT * HH;

    // wave-uniform weight/bias bases for this wave's row block -> s_load path
    const float* wiB = Wih + (size_t)n0 * II;   // row (g,r) at [(g*HH+r)*II]
    const float* whB = Whh + (size_t)n0 * HH;   // row (g,r) at [(g*HH+r)*HH]
    const float* biB = bih + n0;
    const float* bhB = bhh + n0;

    float c[RPW];
#pragma unroll
    for (int r = 0; r < RPW; r++) c[r] = 0.f;

    // zero h buffer 0 (the 4 waves' row sets cover all 30 rows)
#pragma unroll
    for (int r = 0; r < RPW; r++) h_lds[0][n0 + r][lane] = 0.f;

    // x for t=0 (144B, 16B-aligned)
    float4 xr[II / 4];
    {
        const float4* xv = (const float4*)xrow;
#pragma unroll
        for (int q = 0; q < II / 4; q++) xr[q] = xv[q];
    }
    __syncthreads();

    int p = 0;
#pragma unroll 1
    for (int t = 0; t < TT; t++) {
        // ---- x-dot: 32 independent chains, init = bias sum (scalar loads)
        float ax[RPW][4];
#pragma unroll
        for (int r = 0; r < RPW; r++)
#pragma unroll
            for (int g = 0; g < 4; g++)
                ax[r][g] = biB[g * HH + r] + bhB[g * HH + r];

#pragma unroll
        for (int q = 0; q < II / 4; q++) {
            float4 u = xr[q];
#pragma unroll
            for (int r = 0; r < RPW; r++)
#pragma unroll
                for (int g = 0; g < 4; g++) {
                    const float* wi = wiB + (g * HH + r) * II + 4 * q; // uniform
                    ax[r][g] += wi[0] * u.x;
                    ax[r][g] += wi[1] * u.y;
                    ax[r][g] += wi[2] * u.z;
                    ax[r][g] += wi[3] * u.w;
                }
        }

        // ---- refill x in place for t+1 (last x use was above). The load
        // latency hides under the h-dot below, before the barrier.
        if (t + 1 < TT) {
            const float4* xv = (const float4*)(xrow + (t + 1) * II);
#pragma unroll
            for (int q = 0; q < II / 4; q++) xr[q] = xv[q];
        }

        // ---- h-dot in two k-chunks of 15 (caps live hv regs at 15)
#pragma unroll
        for (int half = 0; half < 2; half++) {
            float hv[15];
#pragma unroll
            for (int k = 0; k < 15; k++)
                hv[k] = h_lds[p][half * 15 + k][lane];   // b32, conflict-free
#pragma unroll
            for (int k = 0; k < 15; k++) {
#pragma unroll
                for (int r = 0; r < RPW; r++)
#pragma unroll
                    for (int g = 0; g < 4; g++)
                        ax[r][g] += whB[(g * HH + r) * HH + half * 15 + k] * hv[k];
            }
        }

        // ---- gates, state update, stores (owning wave only: no redundancy)
#pragma unroll
        for (int r = 0; r < RPW; r++) {
            float it = fast_sigmoid(ax[r][0]);
            float ft = fast_sigmoid(ax[r][1]);
            float gt = fast_tanh(ax[r][2]);
            float ot = fast_sigmoid(ax[r][3]);
            float cn = ft * c[r] + it * gt;
            c[r] = cn;
            float hn = ot * fast_tanh(cn);
            h_lds[p ^ 1][n0 + r][lane] = hn;   // dup rows: identical values
            orow[t * HH + n0 + r] = hn;        // b32; L2 merges lines
        }
        __syncthreads();   // h_lds[p^1] complete; also drains x refill (hidden)
        p ^= 1;
    }

    // finals: h from the last-written buffer, c from registers
    float* hN = out + (size_t)BB * TT * HH + (size_t)b * HH;
    float* cN = out + (size_t)BB * TT * HH + (size_t)BB * HH + (size_t)b * HH;
#pragma unroll
    for (int r = 0; r < RPW; r++) {
        hN[n0 + r] = h_lds[p][n0 + r][lane];
        cN[n0 + r] = c[r];
    }
}

extern "C" void kernel_launch(void* const* d_in, const int* in_sizes, int n_in,
                              void* d_out, int out_size, void* d_ws, size_t ws_size,
                              hipStream_t stream) {
    const float* x    = (const float*)d_in[0];
    const float* w_ih = (const float*)d_in[1];
    const float* w_hh = (const float*)d_in[2];
    const float* b_ih = (const float*)d_in[3];
    const float* b_hh = (const float*)d_in[4];
    float* out = (float*)d_out;

    hipLaunchKernelGGL(lstm_fwd, dim3(BB / 64), dim3(256), 0, stream,
                       x, w_ih, w_hh, b_ih, b_hh, out);
}